// Round 8
// baseline (278.360 us; speedup 1.0000x reference)
//
#include <hip/hip_runtime.h>

typedef unsigned short u16;
typedef unsigned int u32;

#define B_GRAPHS 128
#define N_NODES  512
#define D_DIM    256
#define E_EDGES  8192
#define K_TOP    410
#define CSR_STRIDE 12288   // global per-graph edge-list capacity (u16, 8-aligned rows)

typedef __attribute__((ext_vector_type(8))) __bf16 bf16x8;
typedef __attribute__((ext_vector_type(4))) float  f32x4;

__device__ __forceinline__ float bf2f(u16 h) {
  union { u32 u; float f; } c; c.u = ((u32)h) << 16; return c.f;
}
__device__ __forceinline__ float u2f(u32 u) {
  union { u32 u; float f; } c; c.u = u; return c.f;
}
__device__ __forceinline__ u16 f2bf(float f) {
  union { float f; u32 u; } c; c.f = f;
  u32 u = c.u;
  u += 0x7fffu + ((u >> 16) & 1u);   // round-to-nearest-even
  return (u16)(u >> 16);
}
__device__ __forceinline__ void async_copy16(const void* g, void* l) {
  __builtin_amdgcn_global_load_lds((const __attribute__((address_space(1))) void*)g,
                                   (__attribute__((address_space(3))) void*)l, 16, 0, 0);
}

// ---------------------------------------------------------------- zero ------
__global__ void zero_kernel(float* __restrict__ p) {
  *(float4*)&p[(size_t)(blockIdx.x * 256 + threadIdx.x) * 4] = float4{0.f, 0.f, 0.f, 0.f};
}

// ---------------------------------------------------------------- prep ------
// WT layout: [mat][n][k] bf16, mat in {Wr2, Ws2, Wr3, Ws3}
__global__ void prep_kernel(const float* __restrict__ Wr2, const float* __restrict__ Ws2,
                            const float* __restrict__ Wr3, const float* __restrict__ Ws3,
                            u16* __restrict__ WT) {
  const int mat = blockIdx.y;
  const int n = blockIdx.x;
  const int k = threadIdx.x;
  const float* W = (mat == 0) ? Wr2 : (mat == 1) ? Ws2 : (mat == 2) ? Wr3 : Ws3;
  WT[((size_t)mat << 16) + ((size_t)n << 8) + k] = f2bf(W[(size_t)k * 256 + n]);
}

// ---------------------------------------------------------------- csr -------
// Per-graph CSR, rows padded to multiples of 8. Cols stored PRE-SCALED by 32
// (<<5); pad col = 512<<5 = 16384.
__global__ __launch_bounds__(256) void csr_kernel(const int* __restrict__ src,
                                                  const int* __restrict__ dst,
                                                  u16* __restrict__ csr_col,
                                                  u32* __restrict__ csr_off) {
  __shared__ u32 cnt[512];
  __shared__ u32 scan[512];
  __shared__ u32 poff[513];
  const int g = blockIdx.x, t = threadIdx.x;
  const int base = g * N_NODES, ebase = g * E_EDGES;
  for (int i = t; i < 512; i += 256) cnt[i] = 0;
  __syncthreads();
  for (int e = t; e < E_EDGES; e += 256)
    atomicAdd(&cnt[dst[ebase + e] - base], 1u);
  __syncthreads();
  for (int i = t; i < 512; i += 256) scan[i] = (cnt[i] + 7u) & ~7u;
  __syncthreads();
  #pragma unroll 1
  for (int d = 1; d < 512; d <<= 1) {
    const u32 v0 = (t >= d) ? scan[t - d] : 0u;
    const u32 v1 = scan[t + 256 - d];
    __syncthreads();
    if (t >= d) scan[t] += v0;
    scan[t + 256] += v1;
    __syncthreads();
  }
  if (t == 0) poff[0] = 0;
  for (int i = t; i < 512; i += 256) poff[i + 1] = scan[i];
  __syncthreads();
  for (int i = t; i < 513; i += 256) csr_off[(size_t)g * 513 + i] = poff[i];
  for (int i = t; i < 512; i += 256) {
    const u32 s = poff[i] + cnt[i], e2 = poff[i + 1];
    for (u32 k = s; k < e2; ++k) csr_col[(size_t)g * CSR_STRIDE + k] = 16384;
  }
  __syncthreads();
  for (int i = t; i < 512; i += 256) cnt[i] = poff[i];
  __syncthreads();
  for (int e = t; e < E_EDGES; e += 256) {
    const int d = dst[ebase + e] - base;
    const int s = src[ebase + e] - base;
    const u32 pos = atomicAdd(&cnt[d], 1u);
    csr_col[(size_t)g * CSR_STRIDE + pos] = (u16)(s << 5);
  }
}

// ---------------------------------------------------------------- build_a ---
// Dense per-graph adjacency counts, u4-packed: A4[g][dst 512][src 512]/2 bytes.
// Block (c,g): rows c*128..+128. Single-owner LDS u8 rows (no atomics).
__global__ __launch_bounds__(512) void build_a_kernel(const u16* __restrict__ csr_col,
                                                      const u32* __restrict__ csr_off,
                                                      u32* __restrict__ A4) {
  __shared__ unsigned char cnt8[128 * 512];       // 64 KB
  __shared__ __align__(16) u16 colsL[CSR_STRIDE]; // 24 KB
  const int c = blockIdx.x, g = blockIdx.y;
  const int t = threadIdx.x;
  #pragma unroll
  for (int i = 0; i < 8; ++i)
    ((uint4*)cnt8)[i * 512 + t] = uint4{0u, 0u, 0u, 0u};
  for (int i = t; i < CSR_STRIDE / 2; i += 512)
    ((u32*)colsL)[i] = ((const u32*)(csr_col + (size_t)g * CSR_STRIDE))[i];
  __syncthreads();
  if (t < 128) {
    const int row = c * 128 + t;
    const u32 s0 = csr_off[(size_t)g * 513 + row];
    const u32 s1 = csr_off[(size_t)g * 513 + row + 1];
    for (u32 k = s0; k < s1; ++k) {
      const int col = colsL[k] >> 5;
      if (col < 512) cnt8[t * 512 + col]++;
    }
  }
  __syncthreads();
  u32* outp = A4 + (size_t)(g * 512 + c * 128) * 64;
  for (int i = t; i < 8192; i += 512) {
    const u32 lo = ((const u32*)cnt8)[i * 2];
    const u32 hi = ((const u32*)cnt8)[i * 2 + 1];
    const u32 a = lo | (lo >> 4);
    const u32 b = hi | (hi >> 4);
    outp[i] = (a & 0xffu) | ((a >> 8) & 0xff00u) | ((b << 16) & 0xff0000u)
            | ((b << 8) & 0xff000000u);
  }
}

// ---------------------------------------------------------------- conv1 -----
// Block (c,g): graph g, node half c. Cols <<5-scaled -> col = c32 >> 5.
__global__ __launch_bounds__(256) void conv1_kernel(const float* __restrict__ x,
                             const u16* __restrict__ csr_col, const u32* __restrict__ csr_off,
                             const float* __restrict__ Wr1, const float* __restrict__ Ws1,
                             const float* __restrict__ b1,
                             u16* __restrict__ H1, float* __restrict__ X1) {
  __shared__ float xs[513 * 4];        // +zero row 512
  __shared__ float aggs[N_NODES * 5];
  __shared__ __align__(16) u16 cols[CSR_STRIDE];
  __shared__ u32 offs[513];
  const int c = blockIdx.x;            // node half 0/1
  const int g = blockIdx.y;
  const int base = g * N_NODES;
  const int t = threadIdx.x;           // 256 threads

  for (int i = t; i < N_NODES; i += 256)
    *(float4*)&xs[i * 4] = *(const float4*)&x[(size_t)(base + i) * 4];
  if (t < 4) xs[512 * 4 + t] = 0.f;
  for (int i = t; i < CSR_STRIDE / 2; i += 256)
    ((u32*)cols)[i] = ((const u32*)(csr_col + (size_t)g * CSR_STRIDE))[i];
  for (int i = t; i < 513; i += 256) offs[i] = csr_off[(size_t)g * 513 + i];
  __syncthreads();

  #pragma unroll
  for (int nn = 0; nn < 2; ++nn) {
    const int i = t * 2 + nn;
    const u32 s0 = offs[i];
    const int nb = (int)((offs[i + 1] - s0) >> 3);
    float a0 = 0.f, a1 = 0.f, a2 = 0.f, a3 = 0.f;
    for (int b = 0; b < nb; ++b) {
      const uint4 cw = *(const uint4*)&cols[s0 + (u32)b * 8];
      const u32 ww[4] = {cw.x, cw.y, cw.z, cw.w};
      #pragma unroll
      for (int q = 0; q < 4; ++q) {
        const int ca = (int)((ww[q] & 0xffffu) >> 5);
        const int cb = (int)(ww[q] >> 21);
        const float4 va = *(const float4*)&xs[ca * 4];
        const float4 vb = *(const float4*)&xs[cb * 4];
        a0 += va.x + vb.x; a1 += va.y + vb.y;
        a2 += va.z + vb.z; a3 += va.w + vb.w;
      }
    }
    aggs[i * 5 + 0] = a0; aggs[i * 5 + 1] = a1;
    aggs[i * 5 + 2] = a2; aggs[i * 5 + 3] = a3;
  }
  __syncthreads();

  float wr[4], wsv[4];
  #pragma unroll
  for (int k = 0; k < 4; ++k) { wr[k] = Wr1[k * 256 + t]; wsv[k] = Ws1[k * 256 + t]; }
  const float bb = b1[t];
  float mx = 0.f, sm = 0.f;   // relu => >= 0
  const int nlo = c * 256;
  for (int n = nlo; n < nlo + 256; ++n) {
    float acc = bb;
    #pragma unroll
    for (int k = 0; k < 4; ++k) acc += aggs[n * 5 + k] * wr[k] + xs[n * 4 + k] * wsv[k];
    acc = fmaxf(acc, 0.f);
    H1[(size_t)(base + n) * D_DIM + t] = f2bf(acc);
    mx = fmaxf(mx, acc);
    sm += acc;
  }
  atomicMax((int*)&X1[(size_t)g * 512 + t], __float_as_int(mx));
  atomicAdd(&X1[(size_t)g * 512 + 256 + t], sm);   // raw sum; /512 in mlp
}

// ---------------------------------------------------------------- agg_mfma --
// AGG = A_g . H_g via dense bf16 MFMA (A u4 counts, exact in bf16).
// Block: (graph, 128-dst chunk), XCD-chunked. 8 waves = 2 dst-groups x 4
// feat-groups. Per K-step (32 srcs): H-tile staged TRANSPOSED into LDS
// ([feat 256][src 32], 16B-sub XOR swizzle s(feat) = ((feat>>1)&3)^((feat>>3)&3)),
// A-frags decoded from u4 nibbles, 16 MFMA/wave.
__device__ __forceinline__ bf16x8 decode_a4(u32 a) {
  union { u32 w[4]; bf16x8 v; } r;
  #pragma unroll
  for (int p = 0; p < 4; ++p) {
    const float f0 = (float)((a >> (8 * p)) & 15u);
    const float f1 = (float)((a >> (8 * p + 4)) & 15u);
    r.w[p] = (__float_as_uint(f0) >> 16) | (__float_as_uint(f1) & 0xffff0000u);
  }
  return r.v;
}

__global__ __launch_bounds__(512) void agg_mfma_kernel(const u16* __restrict__ H,
                                                       const u32* __restrict__ A4,
                                                       u16* __restrict__ AGG) {
  __shared__ __align__(16) u16 HtL[8192];   // 16 KB transposed tile
  const int bid = blockIdx.x;
  const int lb = (bid >> 3) + (bid & 7) * 64;   // XCD-chunked (512 % 8 == 0)
  const int g = lb >> 2, cdst = lb & 3;
  const int gbase = g * 512;
  const int dstbase = cdst * 128;
  const int t = threadIdx.x;
  const int w = t >> 6, lane = t & 63;
  const int wm = w >> 2, wf = w & 3;          // 2 dst-groups x 4 feat-groups
  const int r16 = lane & 15, gq = lane >> 4;

  // --- staging map: thread t -> (oct = t>>4 in 0..31, sp = t&15 src-pair) ---
  const int oct = t >> 4, sp = t & 15;
  const u16* Hg = H + (size_t)gbase * 256;
  const size_t goff = (size_t)(2 * sp) * 256 + oct * 8;   // row 2sp, feats oct*8
  const int so = (sp >> 2) ^ (oct & 3);
  int wb[4];
  #pragma unroll
  for (int k = 0; k < 4; ++k) wb[k] = oct * 512 + (sp & 3) * 4 + ((so ^ k) << 4);

  // --- read bases (per-lane constant) ---
  const int subE = gq ^ ((r16 >> 1) & 3) ^ (r16 >> 3);
  const int rbE = wf * 4096 + r16 * 64 + (subE << 4);
  const int rbO = wf * 4096 + r16 * 64 + ((subE ^ 2) << 4);

  // --- A pointer ---
  const u32* Ap = A4 + (size_t)(g * 512 + dstbase + wm * 64 + r16) * 64 + gq;

  f32x4 acc[4][4];
  const f32x4 zero = {0.f, 0.f, 0.f, 0.f};
  #pragma unroll
  for (int mi = 0; mi < 4; ++mi)
    #pragma unroll
    for (int ft = 0; ft < 4; ++ft) acc[mi][ft] = zero;

  uint4 rA = *(const uint4*)&Hg[goff];
  uint4 rB = *(const uint4*)&Hg[goff + 256];
  uint4 rAn, rBn;

  #pragma unroll 1
  for (int st = 0; st < 16; ++st) {
    // write phase: 8 packed b32 stores (pair of srcs per write)
    {
      const u32 wa[4] = {rA.x, rA.y, rA.z, rA.w};
      const u32 wbv[4] = {rB.x, rB.y, rB.z, rB.w};
      #pragma unroll
      for (int p = 0; p < 4; ++p) {
        const u32 ve = (wa[p] & 0xffffu) | (wbv[p] << 16);          // j = 2p
        const u32 vo = (wa[p] >> 16) | (wbv[p] & 0xffff0000u);      // j = 2p+1
        *(u32*)((char*)HtL + wb[p] + (2 * p) * 64) = ve;
        *(u32*)((char*)HtL + wb[p] + (2 * p + 1) * 64) = vo;
      }
    }
    asm volatile("s_waitcnt lgkmcnt(0)" ::: "memory");
    __builtin_amdgcn_s_barrier();

    if (st < 15) {
      const size_t noff = goff + (size_t)(st + 1) * 32 * 256;
      rAn = *(const uint4*)&Hg[noff];
      rBn = *(const uint4*)&Hg[noff + 256];
    }

    // A-frags (u4 -> bf16, exact) + B-frags + MFMA
    bf16x8 aF[4];
    #pragma unroll
    for (int mi = 0; mi < 4; ++mi) aF[mi] = decode_a4(Ap[mi * 1024 + st * 4]);
    bf16x8 bF[4];
    bF[0] = *(const bf16x8*)((const char*)HtL + rbE);
    bF[1] = *(const bf16x8*)((const char*)HtL + rbO + 1024);
    bF[2] = *(const bf16x8*)((const char*)HtL + rbE + 2048);
    bF[3] = *(const bf16x8*)((const char*)HtL + rbO + 3072);
    #pragma unroll
    for (int mi = 0; mi < 4; ++mi)
      #pragma unroll
      for (int ft = 0; ft < 4; ++ft)
        acc[mi][ft] = __builtin_amdgcn_mfma_f32_16x16x32_bf16(aF[mi], bF[ft],
                                                              acc[mi][ft], 0, 0, 0);
    __builtin_amdgcn_s_barrier();
    rA = rAn; rB = rBn;
  }

  // epilogue: C/D layout col = lane&15, row = (lane>>4)*4 + reg  [m89]
  #pragma unroll
  for (int mi = 0; mi < 4; ++mi) {
    const size_t rowb = (size_t)(gbase + dstbase + wm * 64 + mi * 16 + gq * 4) * 256;
    #pragma unroll
    for (int ft = 0; ft < 4; ++ft) {
      const int col = wf * 64 + ft * 16 + r16;
      #pragma unroll
      for (int r = 0; r < 4; ++r)
        AGG[rowb + (size_t)r * 256 + col] = f2bf(acc[mi][ft][r]);
    }
  }
}

// ---------------------------------------------------------------- gemm ------
// Hout = relu(Amat @ Wr + Hmat @ Ws + bias). BM=256, 8 waves (4x2), dbuf
// async staging (3 asyncs/wave/stage), counted vmcnt(3), raw s_barrier.
__global__ __launch_bounds__(512) void gemm_kernel(const u16* __restrict__ Amat,
                                                   const u16* __restrict__ Hmat,
                                                   const u16* __restrict__ WrT,
                                                   const u16* __restrict__ WsT,
                                                   const float* __restrict__ bias,
                                                   u16* __restrict__ Hout,
                                                   float* __restrict__ x2pool,
                                                   float* __restrict__ score,
                                                   const float* __restrict__ pvec) {
  __shared__ __align__(16) u16 At[2][256 * 32];
  __shared__ __align__(16) u16 Bt[2][128 * 32];
  const int m0 = blockIdx.x * 256;
  const int n0 = blockIdx.y * 128;
  const int t = threadIdx.x;
  const int wid = t >> 6, lane = t & 63;
  const int wm = wid >> 1, wn = wid & 1;
  const int r16 = lane & 15, q0 = lane >> 4;

  f32x4 acc[4][4];
  const f32x4 zero = {0.f, 0.f, 0.f, 0.f};
  #pragma unroll
  for (int i = 0; i < 4; ++i)
    #pragma unroll
    for (int jj = 0; jj < 4; ++jj) acc[i][jj] = zero;

  const int srow_off = lane >> 2;
  const int sq = lane & 3;

  auto stage = [&](int s) {
    const int buf = s & 1;
    const int ph = s >> 3;
    const int kk = (s & 7) * 32;
    const u16* Ain = ph ? Hmat : Amat;
    const u16* Win = ph ? WsT : WrT;
    #pragma unroll
    for (int j = 0; j < 3; ++j) {
      const int chk = wid * 3 + j;
      if (chk < 16) {
        const int r = chk * 16 + srow_off;
        const int qsrc = sq ^ ((r >> 1) & 3);
        async_copy16(&Ain[(size_t)(m0 + r) * 256 + kk + qsrc * 8], &At[buf][chk * 512]);
      } else {
        const int ch = chk - 16;
        const int r = ch * 16 + srow_off;
        const int qsrc = sq ^ ((r >> 1) & 3);
        async_copy16(&Win[(size_t)(n0 + r) * 256 + kk + qsrc * 8], &Bt[buf][ch * 512]);
      }
    }
  };

  stage(0);
  #pragma unroll 1
  for (int s = 0; s < 16; ++s) {
    if (s < 15) {
      stage(s + 1);
      asm volatile("s_waitcnt vmcnt(3)" ::: "memory");
    } else {
      asm volatile("s_waitcnt vmcnt(0)" ::: "memory");
    }
    __builtin_amdgcn_s_barrier();
    const int buf = s & 1;
    bf16x8 aF[4], bF[4];
    #pragma unroll
    for (int mi = 0; mi < 4; ++mi) {
      const int arow = wm * 64 + mi * 16 + r16;
      const int qs = q0 ^ ((arow >> 1) & 3);
      aF[mi] = *(const bf16x8*)&At[buf][arow * 32 + qs * 8];
    }
    #pragma unroll
    for (int ni = 0; ni < 4; ++ni) {
      const int brow = wn * 64 + ni * 16 + r16;
      const int qs = q0 ^ ((brow >> 1) & 3);
      bF[ni] = *(const bf16x8*)&Bt[buf][brow * 32 + qs * 8];
    }
    #pragma unroll
    for (int mi = 0; mi < 4; ++mi)
      #pragma unroll
      for (int ni = 0; ni < 4; ++ni)
        acc[mi][ni] = __builtin_amdgcn_mfma_f32_16x16x32_bf16(aF[mi], bF[ni],
                                                              acc[mi][ni], 0, 0, 0);
    __builtin_amdgcn_s_barrier();
  }

  const bool do_x2 = (x2pool != nullptr);
  const bool do_sc = (score != nullptr);
  float colmax[4], colsum[4], pv[4], rpart[4][4];
  #pragma unroll
  for (int ni = 0; ni < 4; ++ni) { colmax[ni] = 0.f; colsum[ni] = 0.f; pv[ni] = 0.f; }
  #pragma unroll
  for (int mi = 0; mi < 4; ++mi)
    #pragma unroll
    for (int r = 0; r < 4; ++r) rpart[mi][r] = 0.f;
  if (do_sc) {
    #pragma unroll
    for (int ni = 0; ni < 4; ++ni) pv[ni] = pvec[n0 + wn * 64 + ni * 16 + r16];
  }

  // epilogue: C/D layout col = lane&15, row = (lane>>4)*4 + reg  [m89]
  #pragma unroll
  for (int mi = 0; mi < 4; ++mi) {
    const int growb = m0 + wm * 64 + mi * 16 + q0 * 4;
    #pragma unroll
    for (int ni = 0; ni < 4; ++ni) {
      const int gcol = n0 + wn * 64 + ni * 16 + r16;
      const float bv = bias[gcol];
      #pragma unroll
      for (int r = 0; r < 4; ++r) {
        float v = acc[mi][ni][r] + bv;
        v = fmaxf(v, 0.f);
        Hout[(size_t)(growb + r) * 256 + gcol] = f2bf(v);
        colmax[ni] = fmaxf(colmax[ni], v);
        colsum[ni] += v;
        rpart[mi][r] += v * pv[ni];
      }
    }
  }

  const int gg = m0 >> 9;   // 256-row tile never straddles a graph
  if (do_x2) {
    #pragma unroll
    for (int ni = 0; ni < 4; ++ni) {
      const int gcol = n0 + wn * 64 + ni * 16 + r16;
      float cm = colmax[ni], cs = colsum[ni];
      cm = fmaxf(cm, __shfl_xor(cm, 16));
      cm = fmaxf(cm, __shfl_xor(cm, 32));
      cs += __shfl_xor(cs, 16);
      cs += __shfl_xor(cs, 32);
      if (q0 == 0) {
        atomicMax((int*)&x2pool[(size_t)gg * 512 + gcol], __float_as_int(cm));
        atomicAdd(&x2pool[(size_t)gg * 512 + 256 + gcol], cs);
      }
    }
  }
  if (do_sc) {
    #pragma unroll
    for (int mi = 0; mi < 4; ++mi) {
      const int growb = m0 + wm * 64 + mi * 16 + q0 * 4;
      #pragma unroll
      for (int r = 0; r < 4; ++r) {
        float sp = rpart[mi][r];
        sp += __shfl_xor(sp, 1);
        sp += __shfl_xor(sp, 2);
        sp += __shfl_xor(sp, 4);
        sp += __shfl_xor(sp, 8);
        if (r16 == 0) atomicAdd(&score[growb + r], sp);
      }
    }
  }
}

// ---------------------------------------------------------------- sort ------
__global__ __launch_bounds__(256) void sort_kernel(const float* __restrict__ score,
                                                   const float* __restrict__ p,
                                                   u16* __restrict__ top_idx,
                                                   float* __restrict__ top_scale) {
  __shared__ float sval[N_NODES];
  __shared__ int sidx[N_NODES];
  __shared__ float wsum[4];
  const int g = blockIdx.x, t = threadIdx.x;

  float pvt = p[t];
  float sq2 = pvt * pvt;
  #pragma unroll
  for (int off = 32; off > 0; off >>= 1) sq2 += __shfl_down(sq2, off);
  if ((t & 63) == 0) wsum[t >> 6] = sq2;
  __syncthreads();
  const float inv_pn = 1.f / (sqrtf(wsum[0] + wsum[1] + wsum[2] + wsum[3]) + 1e-16f);

  for (int n = t; n < N_NODES; n += 256) {
    sval[n] = score[(size_t)g * 512 + n] * inv_pn;
    sidx[n] = n;
  }
  __syncthreads();

  for (int k = 2; k <= N_NODES; k <<= 1) {
    for (int jj = k >> 1; jj > 0; jj >>= 1) {
      const int i = ((t & ~(jj - 1)) << 1) | (t & (jj - 1));
      const int ix = i | jj;
      const bool dirDesc = ((i & k) == 0);
      const float vi = sval[i], vx = sval[ix];
      const int ii = sidx[i], ij = sidx[ix];
      const bool iAfter = (vi < vx) || (vi == vx && ii > ij);
      if (dirDesc ? iAfter : !iAfter) {
        sval[i] = vx; sval[ix] = vi;
        sidx[i] = ij; sidx[ix] = ii;
      }
      __syncthreads();
    }
  }

  for (int s = t; s < K_TOP; s += 256) {
    top_idx[(size_t)g * 416 + s] = (u16)sidx[s];
    top_scale[(size_t)g * 416 + s] = tanhf(sval[s]);
  }
}

// ---------------------------------------------------------------- x3 pool ---
__global__ __launch_bounds__(256) void x3_pool_kernel(const u16* __restrict__ H3,
                                                      const u16* __restrict__ top_idx,
                                                      const float* __restrict__ top_scale,
                                                      float* __restrict__ X3) {
  __shared__ u16 sidxL[416];
  __shared__ float ssclL[416];
  __shared__ float redm[32 * 65];
  __shared__ float reds[32 * 65];
  const int c = blockIdx.x;          // 0..3
  const int g = blockIdx.y;
  const int t = threadIdx.x;
  const int fl = t & 7, rg = t >> 3;

  for (int s = t; s < K_TOP; s += 256) {
    sidxL[s] = top_idx[(size_t)g * 416 + s];
    ssclL[s] = top_scale[(size_t)g * 416 + s];
  }
  __syncthreads();

  float mx[8], sm[8];
  #pragma unroll
  for (int j = 0; j < 8; ++j) { mx[j] = -1e30f; sm[j] = 0.f; }
  const size_t rowbase = (size_t)g * 512;
  for (int s = rg; s < K_TOP; s += 32) {
    const int row = sidxL[s];
    const float sc = ssclL[s];
    const uint4 d = *(const uint4*)&H3[(rowbase + row) * 256 + c * 64 + fl * 8];
    const u32 wv[4] = {d.x, d.y, d.z, d.w};
    #pragma unroll
    for (int q = 0; q < 4; ++q) {
      const float v0 = u2f(wv[q] << 16) * sc;
      const float v1 = u2f(wv[q] & 0xffff0000u) * sc;
      mx[q * 2] = fmaxf(mx[q * 2], v0); sm[q * 2] += v0;
      mx[q * 2 + 1] = fmaxf(mx[q * 2 + 1], v1); sm[q * 2 + 1] += v1;
    }
  }
  #pragma unroll
  for (int j = 0; j < 8; ++j) {
    redm[rg * 65 + fl * 8 + j] = mx[j];
    reds[rg * 65 + fl * 8 + j] = sm[j];
  }
  __syncthreads();
  for (int st = 16; st >= 1; st >>= 1) {
    if (rg < st) {
      #pragma unroll
      for (int j = 0; j < 8; ++j) {
        const int a = rg * 65 + fl * 8 + j, b = (rg + st) * 65 + fl * 8 + j;
        redm[a] = fmaxf(redm[a], redm[b]);
        reds[a] += reds[b];
      }
    }
    __syncthreads();
  }
  if (rg == 0) {
    #pragma unroll
    for (int j = 0; j < 8; ++j) {
      X3[(size_t)g * 512 + c * 64 + fl * 8 + j] = redm[fl * 8 + j];
      X3[(size_t)g * 512 + 256 + c * 64 + fl * 8 + j] = reds[fl * 8 + j] * (1.f / (float)K_TOP);
    }
  }
}

// ---------------------------------------------------------------- mlp -------
__global__ void mlp_kernel(const float* __restrict__ X1, const float* __restrict__ X2,
                           const float* __restrict__ X3,
                           const float* __restrict__ W1, const float* __restrict__ c1,
                           const float* __restrict__ W2, const float* __restrict__ c2,
                           const float* __restrict__ W3, const float* __restrict__ c3,
                           float* __restrict__ out) {
  __shared__ float zs[512];
  __shared__ float z1[256];
  __shared__ float z2[128];
  const int g = blockIdx.x, t = threadIdx.x;
  for (int k = t; k < 512; k += 256) {
    const float x1v = X1[(size_t)g * 512 + k];
    const float x2v = X2[(size_t)g * 512 + k];
    const float x3v = X3[(size_t)g * 512 + k];
    zs[k] = (k < 256) ? (x1v + x2v + x3v)
                      : (x1v * (1.f / 512.f) + x2v * (1.f / 512.f) + x3v);
  }
  __syncthreads();
  {
    float acc = c1[t];
    for (int k = 0; k < 512; ++k) acc += zs[k] * W1[(size_t)k * 256 + t];
    z1[t] = fmaxf(acc, 0.f);
  }
  __syncthreads();
  if (t < 128) {
    float acc = c2[t];
    for (int d = 0; d < 256; ++d) acc += z1[d] * W2[(size_t)d * 128 + t];
    z2[t] = fmaxf(acc, 0.f);
  }
  __syncthreads();
  if (t == 0) {
    float acc = c3[0];
    for (int e = 0; e < 128; ++e) acc += z2[e] * W3[e];
    out[g] = 1.f / (1.f + expf(-acc));
  }
}

// ---------------------------------------------------------------- launch ----
extern "C" void kernel_launch(void* const* d_in, const int* in_sizes, int n_in,
                              void* d_out, int out_size, void* d_ws, size_t ws_size,
                              hipStream_t stream) {
  (void)in_sizes; (void)n_in; (void)out_size; (void)ws_size;
  const float* x   = (const float*)d_in[0];
  const int* src   = (const int*)d_in[1];
  const int* dstp  = (const int*)d_in[2];
  const float* Wr1 = (const float*)d_in[3];
  const float* Ws1 = (const float*)d_in[4];
  const float* b1  = (const float*)d_in[5];
  const float* Wr2 = (const float*)d_in[6];
  const float* Ws2 = (const float*)d_in[7];
  const float* b2  = (const float*)d_in[8];
  const float* Wr3 = (const float*)d_in[9];
  const float* Ws3 = (const float*)d_in[10];
  const float* b3  = (const float*)d_in[11];
  const float* pat = (const float*)d_in[12];
  const float* W1  = (const float*)d_in[13];
  const float* c1  = (const float*)d_in[14];
  const float* W2  = (const float*)d_in[15];
  const float* c2  = (const float*)d_in[16];
  const float* W3  = (const float*)d_in[17];
  const float* c3  = (const float*)d_in[18];
  float* out = (float*)d_out;

  char* ws = (char*)d_ws;
  u16* hA  = (u16*)(ws);                 // 32 MB  (h1, later h3)
  u16* hB  = (u16*)(ws + 33554432);      // 32 MB  (h2)
  u16* AGG = (u16*)(ws + 67108864);      // 32 MB
  u16* WT  = (u16*)(ws + 100663296);     // 512 KB
  float* x1 = (float*)(ws + 101187584);  // 256 KB
  float* x2 = (float*)(ws + 101449728);  // 256 KB (contiguous after x1)
  float* x3 = (float*)(ws + 101711872);  // 256 KB
  u16* csr_col = (u16*)(ws + 101974016); // 3 MB
  u32* csr_off = (u32*)(ws + 105119744); // ~263 KB
  u32* A4u     = (u32*)(ws + 105383936); // 16 MB dense u4 adjacency counts
  // aliases into csr_col region (used only after agg#2):
  float* score     = (float*)(ws + 101974016);            // 256 KB
  u16* top_idx     = (u16*)(ws + 101974016 + 262144);     // 104 KB
  float* top_scale = (float*)(ws + 101974016 + 372736);   // 208 KB

  prep_kernel<<<dim3(256, 4), dim3(256), 0, stream>>>(Wr2, Ws2, Wr3, Ws3, WT);
  csr_kernel<<<dim3(128), dim3(256), 0, stream>>>(src, dstp, csr_col, csr_off);
  zero_kernel<<<dim3(128), dim3(256), 0, stream>>>(x1);   // zeros x1 + x2 (contiguous)
  build_a_kernel<<<dim3(4, 128), dim3(512), 0, stream>>>(csr_col, csr_off, A4u);
  conv1_kernel<<<dim3(2, 128), dim3(256), 0, stream>>>(x, csr_col, csr_off, Wr1, Ws1, b1, hA, x1);

  agg_mfma_kernel<<<dim3(512), dim3(512), 0, stream>>>(hA, A4u, AGG);
  gemm_kernel<<<dim3(256, 2), dim3(512), 0, stream>>>(AGG, hA, WT, WT + 65536, b2, hB,
                                                      x2, nullptr, nullptr);

  agg_mfma_kernel<<<dim3(512), dim3(512), 0, stream>>>(hB, A4u, AGG);
  zero_kernel<<<dim3(64), dim3(256), 0, stream>>>(score);
  gemm_kernel<<<dim3(256, 2), dim3(512), 0, stream>>>(AGG, hB, WT + 131072, WT + 196608, b3, hA,
                                                      nullptr, score, pat);

  sort_kernel<<<dim3(128), dim3(256), 0, stream>>>(score, pat, top_idx, top_scale);
  x3_pool_kernel<<<dim3(4, 128), dim3(256), 0, stream>>>(hA, top_idx, top_scale, x3);
  mlp_kernel<<<dim3(128), dim3(256), 0, stream>>>(x1, x2, x3, W1, c1, W2, c2, W3, c3, out);
}

// Round 9
// 264.434 us; speedup vs baseline: 1.0527x; 1.0527x over previous
//
#include <hip/hip_runtime.h>

typedef unsigned short u16;
typedef unsigned int u32;

#define B_GRAPHS 128
#define N_NODES  512
#define D_DIM    256
#define E_EDGES  8192
#define K_TOP    410
#define CSR_STRIDE 12288   // global per-graph edge-list capacity (u16, 8-aligned rows)

typedef __attribute__((ext_vector_type(8))) __bf16 bf16x8;
typedef __attribute__((ext_vector_type(4))) float  f32x4;

__device__ __forceinline__ float bf2f(u16 h) {
  union { u32 u; float f; } c; c.u = ((u32)h) << 16; return c.f;
}
__device__ __forceinline__ float u2f(u32 u) {
  union { u32 u; float f; } c; c.u = u; return c.f;
}
__device__ __forceinline__ u16 f2bf(float f) {
  union { float f; u32 u; } c; c.f = f;
  u32 u = c.u;
  u += 0x7fffu + ((u >> 16) & 1u);   // round-to-nearest-even
  return (u16)(u >> 16);
}
__device__ __forceinline__ void async_copy16(const void* g, void* l) {
  __builtin_amdgcn_global_load_lds((const __attribute__((address_space(1))) void*)g,
                                   (__attribute__((address_space(3))) void*)l, 16, 0, 0);
}

// ---------------------------------------------------------------- zero ------
__global__ void zero_kernel(float* __restrict__ p) {
  *(float4*)&p[(size_t)(blockIdx.x * 256 + threadIdx.x) * 4] = float4{0.f, 0.f, 0.f, 0.f};
}

// ---------------------------------------------------------------- prep ------
// WT layout: [mat][n][k] bf16, mat in {Wr2, Ws2, Wr3, Ws3}
__global__ void prep_kernel(const float* __restrict__ Wr2, const float* __restrict__ Ws2,
                            const float* __restrict__ Wr3, const float* __restrict__ Ws3,
                            u16* __restrict__ WT) {
  const int mat = blockIdx.y;
  const int n = blockIdx.x;
  const int k = threadIdx.x;
  const float* W = (mat == 0) ? Wr2 : (mat == 1) ? Ws2 : (mat == 2) ? Wr3 : Ws3;
  WT[((size_t)mat << 16) + ((size_t)n << 8) + k] = f2bf(W[(size_t)k * 256 + n]);
}

// ---------------------------------------------------------------- csr -------
// Per-graph CSR, rows padded to multiples of 8. Cols stored PRE-SCALED by 32
// (<<5); pad col = 512<<5 = 16384.
__global__ __launch_bounds__(256) void csr_kernel(const int* __restrict__ src,
                                                  const int* __restrict__ dst,
                                                  u16* __restrict__ csr_col,
                                                  u32* __restrict__ csr_off) {
  __shared__ u32 cnt[512];
  __shared__ u32 scan[512];
  __shared__ u32 poff[513];
  const int g = blockIdx.x, t = threadIdx.x;
  const int base = g * N_NODES, ebase = g * E_EDGES;
  for (int i = t; i < 512; i += 256) cnt[i] = 0;
  __syncthreads();
  for (int e = t; e < E_EDGES; e += 256)
    atomicAdd(&cnt[dst[ebase + e] - base], 1u);
  __syncthreads();
  for (int i = t; i < 512; i += 256) scan[i] = (cnt[i] + 7u) & ~7u;
  __syncthreads();
  #pragma unroll 1
  for (int d = 1; d < 512; d <<= 1) {
    const u32 v0 = (t >= d) ? scan[t - d] : 0u;
    const u32 v1 = scan[t + 256 - d];
    __syncthreads();
    if (t >= d) scan[t] += v0;
    scan[t + 256] += v1;
    __syncthreads();
  }
  if (t == 0) poff[0] = 0;
  for (int i = t; i < 512; i += 256) poff[i + 1] = scan[i];
  __syncthreads();
  for (int i = t; i < 513; i += 256) csr_off[(size_t)g * 513 + i] = poff[i];
  for (int i = t; i < 512; i += 256) {
    const u32 s = poff[i] + cnt[i], e2 = poff[i + 1];
    for (u32 k = s; k < e2; ++k) csr_col[(size_t)g * CSR_STRIDE + k] = 16384;
  }
  __syncthreads();
  for (int i = t; i < 512; i += 256) cnt[i] = poff[i];
  __syncthreads();
  for (int e = t; e < E_EDGES; e += 256) {
    const int d = dst[ebase + e] - base;
    const int s = src[ebase + e] - base;
    const u32 pos = atomicAdd(&cnt[d], 1u);
    csr_col[(size_t)g * CSR_STRIDE + pos] = (u16)(s << 5);
  }
}

// ---------------------------------------------------------------- build_a ---
// Dense per-graph adjacency counts, u4-packed, stored in MFMA FRAGMENT ORDER:
// per (g, dst-chunk c): [wm:2][st:16][mi:4][gq:4][r16:16] u32 (32 KB each).
// Word (row, wd) covers dst row c*128+row, srcs wd*8..wd*8+7.
__global__ __launch_bounds__(512) void build_a_kernel(const u16* __restrict__ csr_col,
                                                      const u32* __restrict__ csr_off,
                                                      u32* __restrict__ A4) {
  __shared__ unsigned char cnt8[128 * 512];       // 64 KB
  __shared__ __align__(16) u16 colsL[CSR_STRIDE]; // 24 KB
  const int c = blockIdx.x, g = blockIdx.y;
  const int t = threadIdx.x;
  #pragma unroll
  for (int i = 0; i < 8; ++i)
    ((uint4*)cnt8)[i * 512 + t] = uint4{0u, 0u, 0u, 0u};
  for (int i = t; i < CSR_STRIDE / 2; i += 512)
    ((u32*)colsL)[i] = ((const u32*)(csr_col + (size_t)g * CSR_STRIDE))[i];
  __syncthreads();
  if (t < 128) {
    const int row = c * 128 + t;
    const u32 s0 = csr_off[(size_t)g * 513 + row];
    const u32 s1 = csr_off[(size_t)g * 513 + row + 1];
    for (u32 k = s0; k < s1; ++k) {
      const int col = colsL[k] >> 5;
      if (col < 512) cnt8[t * 512 + col]++;
    }
  }
  __syncthreads();
  u32* outp = A4 + (size_t)(g * 4 + c) * 8192;
  for (int i = t; i < 8192; i += 512) {
    const int row = i >> 6, wd = i & 63;
    const u32 lo = ((const u32*)cnt8)[i * 2];
    const u32 hi = ((const u32*)cnt8)[i * 2 + 1];
    const u32 a = lo | (lo >> 4);
    const u32 b = hi | (hi >> 4);
    const u32 word = (a & 0xffu) | ((a >> 8) & 0xff00u) | ((b << 16) & 0xff0000u)
                   | ((b << 8) & 0xff000000u);
    const int wm2 = row >> 6, mi = (row >> 4) & 3, r16v = row & 15;
    const int stv = wd >> 2, gqv = wd & 3;
    outp[wm2 * 4096 + stv * 256 + mi * 64 + gqv * 16 + r16v] = word;
  }
}

// ---------------------------------------------------------------- conv1 -----
// Block (c,g): graph g, node half c. Cols <<5-scaled -> col = c32 >> 5.
__global__ __launch_bounds__(256) void conv1_kernel(const float* __restrict__ x,
                             const u16* __restrict__ csr_col, const u32* __restrict__ csr_off,
                             const float* __restrict__ Wr1, const float* __restrict__ Ws1,
                             const float* __restrict__ b1,
                             u16* __restrict__ H1, float* __restrict__ X1) {
  __shared__ float xs[513 * 4];        // +zero row 512
  __shared__ float aggs[N_NODES * 5];
  __shared__ __align__(16) u16 cols[CSR_STRIDE];
  __shared__ u32 offs[513];
  const int c = blockIdx.x;            // node half 0/1
  const int g = blockIdx.y;
  const int base = g * N_NODES;
  const int t = threadIdx.x;           // 256 threads

  for (int i = t; i < N_NODES; i += 256)
    *(float4*)&xs[i * 4] = *(const float4*)&x[(size_t)(base + i) * 4];
  if (t < 4) xs[512 * 4 + t] = 0.f;
  for (int i = t; i < CSR_STRIDE / 2; i += 256)
    ((u32*)cols)[i] = ((const u32*)(csr_col + (size_t)g * CSR_STRIDE))[i];
  for (int i = t; i < 513; i += 256) offs[i] = csr_off[(size_t)g * 513 + i];
  __syncthreads();

  #pragma unroll
  for (int nn = 0; nn < 2; ++nn) {
    const int i = t * 2 + nn;
    const u32 s0 = offs[i];
    const int nb = (int)((offs[i + 1] - s0) >> 3);
    float a0 = 0.f, a1 = 0.f, a2 = 0.f, a3 = 0.f;
    for (int b = 0; b < nb; ++b) {
      const uint4 cw = *(const uint4*)&cols[s0 + (u32)b * 8];
      const u32 ww[4] = {cw.x, cw.y, cw.z, cw.w};
      #pragma unroll
      for (int q = 0; q < 4; ++q) {
        const int ca = (int)((ww[q] & 0xffffu) >> 5);
        const int cb = (int)(ww[q] >> 21);
        const float4 va = *(const float4*)&xs[ca * 4];
        const float4 vb = *(const float4*)&xs[cb * 4];
        a0 += va.x + vb.x; a1 += va.y + vb.y;
        a2 += va.z + vb.z; a3 += va.w + vb.w;
      }
    }
    aggs[i * 5 + 0] = a0; aggs[i * 5 + 1] = a1;
    aggs[i * 5 + 2] = a2; aggs[i * 5 + 3] = a3;
  }
  __syncthreads();

  float wr[4], wsv[4];
  #pragma unroll
  for (int k = 0; k < 4; ++k) { wr[k] = Wr1[k * 256 + t]; wsv[k] = Ws1[k * 256 + t]; }
  const float bb = b1[t];
  float mx = 0.f, sm = 0.f;   // relu => >= 0
  const int nlo = c * 256;
  for (int n = nlo; n < nlo + 256; ++n) {
    float acc = bb;
    #pragma unroll
    for (int k = 0; k < 4; ++k) acc += aggs[n * 5 + k] * wr[k] + xs[n * 4 + k] * wsv[k];
    acc = fmaxf(acc, 0.f);
    H1[(size_t)(base + n) * D_DIM + t] = f2bf(acc);
    mx = fmaxf(mx, acc);
    sm += acc;
  }
  atomicMax((int*)&X1[(size_t)g * 512 + t], __float_as_int(mx));
  atomicAdd(&X1[(size_t)g * 512 + 256 + t], sm);   // raw sum; /512 in mlp
}

// ---------------------------------------------------------------- agg_mfma --
// AGG = A_g . H_g via dense bf16 MFMA (A u4 counts, exact in bf16).
// A loads are now COALESCED (fragment-order A4) + register-prefetched one
// step ahead; H-tile staged transposed into LDS as before.
__device__ __forceinline__ bf16x8 decode_a4(u32 a) {
  union { u32 w[4]; bf16x8 v; } r;
  #pragma unroll
  for (int p = 0; p < 4; ++p) {
    const float f0 = (float)((a >> (8 * p)) & 15u);
    const float f1 = (float)((a >> (8 * p + 4)) & 15u);
    r.w[p] = (__float_as_uint(f0) >> 16) | (__float_as_uint(f1) & 0xffff0000u);
  }
  return r.v;
}

__global__ __launch_bounds__(512) void agg_mfma_kernel(const u16* __restrict__ H,
                                                       const u32* __restrict__ A4,
                                                       u16* __restrict__ AGG) {
  __shared__ __align__(16) u16 HtL[8192];   // 16 KB transposed tile
  const int bid = blockIdx.x;
  const int lb = (bid >> 3) + (bid & 7) * 64;   // XCD-chunked (512 % 8 == 0)
  const int g = lb >> 2, cdst = lb & 3;
  const int gbase = g * 512;
  const int dstbase = cdst * 128;
  const int t = threadIdx.x;
  const int w = t >> 6, lane = t & 63;
  const int wm = w >> 2, wf = w & 3;          // 2 dst-groups x 4 feat-groups
  const int r16 = lane & 15, gq = lane >> 4;

  // --- staging map: thread t -> (oct = t>>4 in 0..31, sp = t&15 src-pair) ---
  const int oct = t >> 4, sp = t & 15;
  const u16* Hg = H + (size_t)gbase * 256;
  const size_t goff = (size_t)(2 * sp) * 256 + oct * 8;   // row 2sp, feats oct*8
  const int so = (sp >> 2) ^ (oct & 3);
  int wb[4];
  #pragma unroll
  for (int k = 0; k < 4; ++k) wb[k] = oct * 512 + (sp & 3) * 4 + ((so ^ k) << 4);

  // --- read bases (per-lane constant) ---
  const int subE = gq ^ ((r16 >> 1) & 3) ^ (r16 >> 3);
  const int rbE = wf * 4096 + r16 * 64 + (subE << 4);
  const int rbO = wf * 4096 + r16 * 64 + ((subE ^ 2) << 4);

  // --- A pointer: fragment-order layout, per-lane coalesced ---
  const u32* ApB = A4 + (size_t)(g * 4 + cdst) * 8192 + wm * 4096 + lane;

  f32x4 acc[4][4];
  const f32x4 zero = {0.f, 0.f, 0.f, 0.f};
  #pragma unroll
  for (int mi = 0; mi < 4; ++mi)
    #pragma unroll
    for (int ft = 0; ft < 4; ++ft) acc[mi][ft] = zero;

  uint4 rA = *(const uint4*)&Hg[goff];
  uint4 rB = *(const uint4*)&Hg[goff + 256];
  u32 aw[4], awn[4];
  #pragma unroll
  for (int mi = 0; mi < 4; ++mi) aw[mi] = ApB[mi * 64];
  uint4 rAn, rBn;

  #pragma unroll 1
  for (int st = 0; st < 16; ++st) {
    // issue next-step loads FIRST (full-iteration latency cover)
    if (st < 15) {
      const size_t noff = goff + (size_t)(st + 1) * 32 * 256;
      rAn = *(const uint4*)&Hg[noff];
      rBn = *(const uint4*)&Hg[noff + 256];
      #pragma unroll
      for (int mi = 0; mi < 4; ++mi) awn[mi] = ApB[(st + 1) * 256 + mi * 64];
    }

    // write phase: 8 packed b32 stores (pair of srcs per write)
    {
      const u32 wa[4] = {rA.x, rA.y, rA.z, rA.w};
      const u32 wbv[4] = {rB.x, rB.y, rB.z, rB.w};
      #pragma unroll
      for (int p = 0; p < 4; ++p) {
        const u32 ve = (wa[p] & 0xffffu) | (wbv[p] << 16);          // j = 2p
        const u32 vo = (wa[p] >> 16) | (wbv[p] & 0xffff0000u);      // j = 2p+1
        *(u32*)((char*)HtL + wb[p] + (2 * p) * 64) = ve;
        *(u32*)((char*)HtL + wb[p] + (2 * p + 1) * 64) = vo;
      }
    }
    asm volatile("s_waitcnt lgkmcnt(0)" ::: "memory");
    __builtin_amdgcn_s_barrier();

    // A-frags (u4 -> bf16, exact) + B-frags + MFMA
    bf16x8 aF[4];
    #pragma unroll
    for (int mi = 0; mi < 4; ++mi) aF[mi] = decode_a4(aw[mi]);
    bf16x8 bF[4];
    bF[0] = *(const bf16x8*)((const char*)HtL + rbE);
    bF[1] = *(const bf16x8*)((const char*)HtL + rbO + 1024);
    bF[2] = *(const bf16x8*)((const char*)HtL + rbE + 2048);
    bF[3] = *(const bf16x8*)((const char*)HtL + rbO + 3072);
    #pragma unroll
    for (int mi = 0; mi < 4; ++mi)
      #pragma unroll
      for (int ft = 0; ft < 4; ++ft)
        acc[mi][ft] = __builtin_amdgcn_mfma_f32_16x16x32_bf16(aF[mi], bF[ft],
                                                              acc[mi][ft], 0, 0, 0);
    __builtin_amdgcn_s_barrier();
    rA = rAn; rB = rBn;
    #pragma unroll
    for (int mi = 0; mi < 4; ++mi) aw[mi] = awn[mi];
  }

  // epilogue: C/D layout col = lane&15, row = (lane>>4)*4 + reg  [m89]
  #pragma unroll
  for (int mi = 0; mi < 4; ++mi) {
    const size_t rowb = (size_t)(gbase + dstbase + wm * 64 + mi * 16 + gq * 4) * 256;
    #pragma unroll
    for (int ft = 0; ft < 4; ++ft) {
      const int col = wf * 64 + ft * 16 + r16;
      #pragma unroll
      for (int r = 0; r < 4; ++r)
        AGG[rowb + (size_t)r * 256 + col] = f2bf(acc[mi][ft][r]);
    }
  }
}

// ---------------------------------------------------------------- gemm ------
// Hout = relu(Amat @ Wr + Hmat @ Ws + bias). BM=256, 8 waves (4x2), dbuf
// async staging (3 asyncs/wave/stage), counted vmcnt(3), raw s_barrier.
__global__ __launch_bounds__(512) void gemm_kernel(const u16* __restrict__ Amat,
                                                   const u16* __restrict__ Hmat,
                                                   const u16* __restrict__ WrT,
                                                   const u16* __restrict__ WsT,
                                                   const float* __restrict__ bias,
                                                   u16* __restrict__ Hout,
                                                   float* __restrict__ x2pool,
                                                   float* __restrict__ score,
                                                   const float* __restrict__ pvec) {
  __shared__ __align__(16) u16 At[2][256 * 32];
  __shared__ __align__(16) u16 Bt[2][128 * 32];
  const int m0 = blockIdx.x * 256;
  const int n0 = blockIdx.y * 128;
  const int t = threadIdx.x;
  const int wid = t >> 6, lane = t & 63;
  const int wm = wid >> 1, wn = wid & 1;
  const int r16 = lane & 15, q0 = lane >> 4;

  f32x4 acc[4][4];
  const f32x4 zero = {0.f, 0.f, 0.f, 0.f};
  #pragma unroll
  for (int i = 0; i < 4; ++i)
    #pragma unroll
    for (int jj = 0; jj < 4; ++jj) acc[i][jj] = zero;

  const int srow_off = lane >> 2;
  const int sq = lane & 3;

  auto stage = [&](int s) {
    const int buf = s & 1;
    const int ph = s >> 3;
    const int kk = (s & 7) * 32;
    const u16* Ain = ph ? Hmat : Amat;
    const u16* Win = ph ? WsT : WrT;
    #pragma unroll
    for (int j = 0; j < 3; ++j) {
      const int chk = wid * 3 + j;
      if (chk < 16) {
        const int r = chk * 16 + srow_off;
        const int qsrc = sq ^ ((r >> 1) & 3);
        async_copy16(&Ain[(size_t)(m0 + r) * 256 + kk + qsrc * 8], &At[buf][chk * 512]);
      } else {
        const int ch = chk - 16;
        const int r = ch * 16 + srow_off;
        const int qsrc = sq ^ ((r >> 1) & 3);
        async_copy16(&Win[(size_t)(n0 + r) * 256 + kk + qsrc * 8], &Bt[buf][ch * 512]);
      }
    }
  };

  stage(0);
  #pragma unroll 1
  for (int s = 0; s < 16; ++s) {
    if (s < 15) {
      stage(s + 1);
      asm volatile("s_waitcnt vmcnt(3)" ::: "memory");
    } else {
      asm volatile("s_waitcnt vmcnt(0)" ::: "memory");
    }
    __builtin_amdgcn_s_barrier();
    const int buf = s & 1;
    bf16x8 aF[4], bF[4];
    #pragma unroll
    for (int mi = 0; mi < 4; ++mi) {
      const int arow = wm * 64 + mi * 16 + r16;
      const int qs = q0 ^ ((arow >> 1) & 3);
      aF[mi] = *(const bf16x8*)&At[buf][arow * 32 + qs * 8];
    }
    #pragma unroll
    for (int ni = 0; ni < 4; ++ni) {
      const int brow = wn * 64 + ni * 16 + r16;
      const int qs = q0 ^ ((brow >> 1) & 3);
      bF[ni] = *(const bf16x8*)&Bt[buf][brow * 32 + qs * 8];
    }
    #pragma unroll
    for (int mi = 0; mi < 4; ++mi)
      #pragma unroll
      for (int ni = 0; ni < 4; ++ni)
        acc[mi][ni] = __builtin_amdgcn_mfma_f32_16x16x32_bf16(aF[mi], bF[ni],
                                                              acc[mi][ni], 0, 0, 0);
    __builtin_amdgcn_s_barrier();
  }

  const bool do_x2 = (x2pool != nullptr);
  const bool do_sc = (score != nullptr);
  float colmax[4], colsum[4], pv[4], rpart[4][4];
  #pragma unroll
  for (int ni = 0; ni < 4; ++ni) { colmax[ni] = 0.f; colsum[ni] = 0.f; pv[ni] = 0.f; }
  #pragma unroll
  for (int mi = 0; mi < 4; ++mi)
    #pragma unroll
    for (int r = 0; r < 4; ++r) rpart[mi][r] = 0.f;
  if (do_sc) {
    #pragma unroll
    for (int ni = 0; ni < 4; ++ni) pv[ni] = pvec[n0 + wn * 64 + ni * 16 + r16];
  }

  // epilogue: C/D layout col = lane&15, row = (lane>>4)*4 + reg  [m89]
  #pragma unroll
  for (int mi = 0; mi < 4; ++mi) {
    const int growb = m0 + wm * 64 + mi * 16 + q0 * 4;
    #pragma unroll
    for (int ni = 0; ni < 4; ++ni) {
      const int gcol = n0 + wn * 64 + ni * 16 + r16;
      const float bv = bias[gcol];
      #pragma unroll
      for (int r = 0; r < 4; ++r) {
        float v = acc[mi][ni][r] + bv;
        v = fmaxf(v, 0.f);
        Hout[(size_t)(growb + r) * 256 + gcol] = f2bf(v);
        colmax[ni] = fmaxf(colmax[ni], v);
        colsum[ni] += v;
        rpart[mi][r] += v * pv[ni];
      }
    }
  }

  const int gg = m0 >> 9;   // 256-row tile never straddles a graph
  if (do_x2) {
    #pragma unroll
    for (int ni = 0; ni < 4; ++ni) {
      const int gcol = n0 + wn * 64 + ni * 16 + r16;
      float cm = colmax[ni], cs = colsum[ni];
      cm = fmaxf(cm, __shfl_xor(cm, 16));
      cm = fmaxf(cm, __shfl_xor(cm, 32));
      cs += __shfl_xor(cs, 16);
      cs += __shfl_xor(cs, 32);
      if (q0 == 0) {
        atomicMax((int*)&x2pool[(size_t)gg * 512 + gcol], __float_as_int(cm));
        atomicAdd(&x2pool[(size_t)gg * 512 + 256 + gcol], cs);
      }
    }
  }
  if (do_sc) {
    #pragma unroll
    for (int mi = 0; mi < 4; ++mi) {
      const int growb = m0 + wm * 64 + mi * 16 + q0 * 4;
      #pragma unroll
      for (int r = 0; r < 4; ++r) {
        float sp = rpart[mi][r];
        sp += __shfl_xor(sp, 1);
        sp += __shfl_xor(sp, 2);
        sp += __shfl_xor(sp, 4);
        sp += __shfl_xor(sp, 8);
        if (r16 == 0) atomicAdd(&score[growb + r], sp);
      }
    }
  }
}

// ---------------------------------------------------------------- sort ------
__global__ __launch_bounds__(256) void sort_kernel(const float* __restrict__ score,
                                                   const float* __restrict__ p,
                                                   u16* __restrict__ top_idx,
                                                   float* __restrict__ top_scale) {
  __shared__ float sval[N_NODES];
  __shared__ int sidx[N_NODES];
  __shared__ float wsum[4];
  const int g = blockIdx.x, t = threadIdx.x;

  float pvt = p[t];
  float sq2 = pvt * pvt;
  #pragma unroll
  for (int off = 32; off > 0; off >>= 1) sq2 += __shfl_down(sq2, off);
  if ((t & 63) == 0) wsum[t >> 6] = sq2;
  __syncthreads();
  const float inv_pn = 1.f / (sqrtf(wsum[0] + wsum[1] + wsum[2] + wsum[3]) + 1e-16f);

  for (int n = t; n < N_NODES; n += 256) {
    sval[n] = score[(size_t)g * 512 + n] * inv_pn;
    sidx[n] = n;
  }
  __syncthreads();

  for (int k = 2; k <= N_NODES; k <<= 1) {
    for (int jj = k >> 1; jj > 0; jj >>= 1) {
      const int i = ((t & ~(jj - 1)) << 1) | (t & (jj - 1));
      const int ix = i | jj;
      const bool dirDesc = ((i & k) == 0);
      const float vi = sval[i], vx = sval[ix];
      const int ii = sidx[i], ij = sidx[ix];
      const bool iAfter = (vi < vx) || (vi == vx && ii > ij);
      if (dirDesc ? iAfter : !iAfter) {
        sval[i] = vx; sval[ix] = vi;
        sidx[i] = ij; sidx[ix] = ii;
      }
      __syncthreads();
    }
  }

  for (int s = t; s < K_TOP; s += 256) {
    top_idx[(size_t)g * 416 + s] = (u16)sidx[s];
    top_scale[(size_t)g * 416 + s] = tanhf(sval[s]);
  }
}

// ---------------------------------------------------------------- x3 pool ---
__global__ __launch_bounds__(256) void x3_pool_kernel(const u16* __restrict__ H3,
                                                      const u16* __restrict__ top_idx,
                                                      const float* __restrict__ top_scale,
                                                      float* __restrict__ X3) {
  __shared__ u16 sidxL[416];
  __shared__ float ssclL[416];
  __shared__ float redm[32 * 65];
  __shared__ float reds[32 * 65];
  const int c = blockIdx.x;          // 0..3
  const int g = blockIdx.y;
  const int t = threadIdx.x;
  const int fl = t & 7, rg = t >> 3;

  for (int s = t; s < K_TOP; s += 256) {
    sidxL[s] = top_idx[(size_t)g * 416 + s];
    ssclL[s] = top_scale[(size_t)g * 416 + s];
  }
  __syncthreads();

  float mx[8], sm[8];
  #pragma unroll
  for (int j = 0; j < 8; ++j) { mx[j] = -1e30f; sm[j] = 0.f; }
  const size_t rowbase = (size_t)g * 512;
  for (int s = rg; s < K_TOP; s += 32) {
    const int row = sidxL[s];
    const float sc = ssclL[s];
    const uint4 d = *(const uint4*)&H3[(rowbase + row) * 256 + c * 64 + fl * 8];
    const u32 wv[4] = {d.x, d.y, d.z, d.w};
    #pragma unroll
    for (int q = 0; q < 4; ++q) {
      const float v0 = u2f(wv[q] << 16) * sc;
      const float v1 = u2f(wv[q] & 0xffff0000u) * sc;
      mx[q * 2] = fmaxf(mx[q * 2], v0); sm[q * 2] += v0;
      mx[q * 2 + 1] = fmaxf(mx[q * 2 + 1], v1); sm[q * 2 + 1] += v1;
    }
  }
  #pragma unroll
  for (int j = 0; j < 8; ++j) {
    redm[rg * 65 + fl * 8 + j] = mx[j];
    reds[rg * 65 + fl * 8 + j] = sm[j];
  }
  __syncthreads();
  for (int st = 16; st >= 1; st >>= 1) {
    if (rg < st) {
      #pragma unroll
      for (int j = 0; j < 8; ++j) {
        const int a = rg * 65 + fl * 8 + j, b = (rg + st) * 65 + fl * 8 + j;
        redm[a] = fmaxf(redm[a], redm[b]);
        reds[a] += reds[b];
      }
    }
    __syncthreads();
  }
  if (rg == 0) {
    #pragma unroll
    for (int j = 0; j < 8; ++j) {
      X3[(size_t)g * 512 + c * 64 + fl * 8 + j] = redm[fl * 8 + j];
      X3[(size_t)g * 512 + 256 + c * 64 + fl * 8 + j] = reds[fl * 8 + j] * (1.f / (float)K_TOP);
    }
  }
}

// ---------------------------------------------------------------- mlp -------
__global__ void mlp_kernel(const float* __restrict__ X1, const float* __restrict__ X2,
                           const float* __restrict__ X3,
                           const float* __restrict__ W1, const float* __restrict__ c1,
                           const float* __restrict__ W2, const float* __restrict__ c2,
                           const float* __restrict__ W3, const float* __restrict__ c3,
                           float* __restrict__ out) {
  __shared__ float zs[512];
  __shared__ float z1[256];
  __shared__ float z2[128];
  const int g = blockIdx.x, t = threadIdx.x;
  for (int k = t; k < 512; k += 256) {
    const float x1v = X1[(size_t)g * 512 + k];
    const float x2v = X2[(size_t)g * 512 + k];
    const float x3v = X3[(size_t)g * 512 + k];
    zs[k] = (k < 256) ? (x1v + x2v + x3v)
                      : (x1v * (1.f / 512.f) + x2v * (1.f / 512.f) + x3v);
  }
  __syncthreads();
  {
    float acc = c1[t];
    for (int k = 0; k < 512; ++k) acc += zs[k] * W1[(size_t)k * 256 + t];
    z1[t] = fmaxf(acc, 0.f);
  }
  __syncthreads();
  if (t < 128) {
    float acc = c2[t];
    for (int d = 0; d < 256; ++d) acc += z1[d] * W2[(size_t)d * 128 + t];
    z2[t] = fmaxf(acc, 0.f);
  }
  __syncthreads();
  if (t == 0) {
    float acc = c3[0];
    for (int e = 0; e < 128; ++e) acc += z2[e] * W3[e];
    out[g] = 1.f / (1.f + expf(-acc));
  }
}

// ---------------------------------------------------------------- launch ----
extern "C" void kernel_launch(void* const* d_in, const int* in_sizes, int n_in,
                              void* d_out, int out_size, void* d_ws, size_t ws_size,
                              hipStream_t stream) {
  (void)in_sizes; (void)n_in; (void)out_size; (void)ws_size;
  const float* x   = (const float*)d_in[0];
  const int* src   = (const int*)d_in[1];
  const int* dstp  = (const int*)d_in[2];
  const float* Wr1 = (const float*)d_in[3];
  const float* Ws1 = (const float*)d_in[4];
  const float* b1  = (const float*)d_in[5];
  const float* Wr2 = (const float*)d_in[6];
  const float* Ws2 = (const float*)d_in[7];
  const float* b2  = (const float*)d_in[8];
  const float* Wr3 = (const float*)d_in[9];
  const float* Ws3 = (const float*)d_in[10];
  const float* b3  = (const float*)d_in[11];
  const float* pat = (const float*)d_in[12];
  const float* W1  = (const float*)d_in[13];
  const float* c1  = (const float*)d_in[14];
  const float* W2  = (const float*)d_in[15];
  const float* c2  = (const float*)d_in[16];
  const float* W3  = (const float*)d_in[17];
  const float* c3  = (const float*)d_in[18];
  float* out = (float*)d_out;

  char* ws = (char*)d_ws;
  u16* hA  = (u16*)(ws);                 // 32 MB  (h1, later h3)
  u16* hB  = (u16*)(ws + 33554432);      // 32 MB  (h2)
  u16* AGG = (u16*)(ws + 67108864);      // 32 MB
  u16* WT  = (u16*)(ws + 100663296);     // 512 KB
  float* x1 = (float*)(ws + 101187584);  // 256 KB
  float* x2 = (float*)(ws + 101449728);  // 256 KB (contiguous after x1)
  float* x3 = (float*)(ws + 101711872);  // 256 KB
  u16* csr_col = (u16*)(ws + 101974016); // 3 MB
  u32* csr_off = (u32*)(ws + 105119744); // ~263 KB
  u32* A4u     = (u32*)(ws + 105383936); // 16 MB dense u4 adjacency (fragment order)
  // aliases into csr_col region (used only after agg#2):
  float* score     = (float*)(ws + 101974016);            // 256 KB
  u16* top_idx     = (u16*)(ws + 101974016 + 262144);     // 104 KB
  float* top_scale = (float*)(ws + 101974016 + 372736);   // 208 KB

  prep_kernel<<<dim3(256, 4), dim3(256), 0, stream>>>(Wr2, Ws2, Wr3, Ws3, WT);
  csr_kernel<<<dim3(128), dim3(256), 0, stream>>>(src, dstp, csr_col, csr_off);
  zero_kernel<<<dim3(128), dim3(256), 0, stream>>>(x1);   // zeros x1 + x2 (contiguous)
  build_a_kernel<<<dim3(4, 128), dim3(512), 0, stream>>>(csr_col, csr_off, A4u);
  conv1_kernel<<<dim3(2, 128), dim3(256), 0, stream>>>(x, csr_col, csr_off, Wr1, Ws1, b1, hA, x1);

  agg_mfma_kernel<<<dim3(512), dim3(512), 0, stream>>>(hA, A4u, AGG);
  gemm_kernel<<<dim3(256, 2), dim3(512), 0, stream>>>(AGG, hA, WT, WT + 65536, b2, hB,
                                                      x2, nullptr, nullptr);

  agg_mfma_kernel<<<dim3(512), dim3(512), 0, stream>>>(hB, A4u, AGG);
  zero_kernel<<<dim3(64), dim3(256), 0, stream>>>(score);
  gemm_kernel<<<dim3(256, 2), dim3(512), 0, stream>>>(AGG, hB, WT + 131072, WT + 196608, b3, hA,
                                                      nullptr, score, pat);

  sort_kernel<<<dim3(128), dim3(256), 0, stream>>>(score, pat, top_idx, top_scale);
  x3_pool_kernel<<<dim3(4, 128), dim3(256), 0, stream>>>(hA, top_idx, top_scale, x3);
  mlp_kernel<<<dim3(128), dim3(256), 0, stream>>>(x1, x2, x3, W1, c1, W2, c2, W3, c3, out);
}